// Round 9
// baseline (2234.898 us; speedup 1.0000x reference)
//
#include <hip/hip_runtime.h>
#include <stdint.h>

#define HW    16384
#define NB    64
#define PROW  132
#define PLSZ  (130*132)
#define CSTR  64                       // NHWC ch stride: ch0-31 = hi, ch32-63 = lo
#define BUFEL ((long)PLSZ * CSTR)      // ushorts per buffer-sample
#define WSMP  167936                   // weight ushorts per sample (82 slots * 2048)
#define EPSB  1e-5f

typedef __attribute__((ext_vector_type(8))) short bf8;
typedef __attribute__((ext_vector_type(4))) short s4v;
typedef __attribute__((ext_vector_type(4))) float f4v;

__device__ __forceinline__ unsigned short f2bf(float f){
    unsigned u = __float_as_uint(f);
    u = (u + 0x7FFFu + ((u >> 16) & 1u)) >> 16;   // RNE
    return (unsigned short)u;
}
__device__ __forceinline__ float bf2f(unsigned short h){
    return __uint_as_float(((unsigned)h) << 16);
}

// ---- prep: per-sample weights -> bf16 hi/lo, BN-folded, laid out
// [smp][slot][o(32)][c(32)] with hi at +0, lo at +1024. Slot = layer*9+shift
// (layers 0-8), slot 81 = final 1x1. L0's x-weights placed at c=12-21 (x
// lives at ch12-21 of buffer C); all padding positions are ZERO.
__global__ void prep_w(const float* __restrict__ w1, const float* __restrict__ w2,
                       const float* __restrict__ w3, const float* __restrict__ w4,
                       const float* __restrict__ g,  const float* __restrict__ be,
                       const float* __restrict__ mu, const float* __restrict__ va,
                       unsigned short* __restrict__ wout, float* __restrict__ bias)
{
    const int START[10] = {0,1080,2376,3672,8424,13608,16200,20952,26136,28728};
    const int COt[10] = {12,12,12,24,24,12,24,24,12,11};
    const int CIt[10] = {10,12,12,22,24,24,22,24,24,22};
    const int BNo[10] = {0,12,24,36,60,84,96,120,144,0};
    long tid = (long)blockIdx.x*256 + threadIdx.x;
    long total = (long)NB * 82 * 1024;
    for (long e = tid; e < total; e += (long)gridDim.x*256) {
        int  i    = (int)(e & 1023);
        long r    = e >> 10;
        int  slot = (int)(r % 82);
        int  smp  = (int)(r / 82);
        int  l  = slot < 81 ? slot / 9 : 9;
        int  sh = slot < 81 ? slot % 9 : 0;
        int  o = i >> 5, c = i & 31;
        int  CO = COt[l], CI = CIt[l];
        float v = 0.f;
        bool ok; int csrc = c;
        if (l == 0) { ok = (o < 12) && (c >= 12) && (c < 22); csrc = c - 12; }
        else        { ok = (o < CO) && (c < CI); }
        if (ok) {
            int p = (l < 9) ? START[l] + (o*CI + csrc)*9 + sh
                            : START[9] + o*22 + csrc;
            const float* src; long si;
            if      (p <  3672) { src = w1; si = (long)smp*3672  + p; }
            else if (p < 16200) { src = w2; si = (long)smp*12528 + (p-3672); }
            else if (p < 28728) { src = w3; si = (long)smp*12528 + (p-16200); }
            else                { src = w4; si = (long)smp*242   + (p-28728); }
            v = src[si];
            if (l < 9) v *= g[BNo[l]+o] * rsqrtf(va[BNo[l]+o] + EPSB);
        }
        unsigned short hb = f2bf(v);
        unsigned short lb = f2bf(v - bf2f(hb));
        long base = (long)smp*WSMP + (long)slot*2048 + o*32 + c;
        wout[base]        = hb;
        wout[base + 1024] = lb;
    }
    if (tid < 256) {   // bias padded to 256, zeros beyond 156
        float b = 0.f;
        if (tid < 156) {
            float s = g[tid] * rsqrtf(va[tid] + EPSB);
            b = be[tid] - mu[tid]*s;
        }
        bias[(int)tid] = b;
    }
}

// ---- zero spatial borders (all 64 ch) of every buffer-plane. Interior
// padding channels are neutralized by zero WEIGHTS (finite poison * 0 = 0).
__global__ void zbord(unsigned short* __restrict__ base)
{
    unsigned short* p = base + (long)blockIdx.x * BUFEL;
    for (int k = threadIdx.x; k < 776*64; k += 256) {
        int j = k >> 6, ch = k & 63;
        int idx;
        if      (j < 132) idx = j;
        else if (j < 264) idx = 129*PROW + (j-132);
        else { int q = j - 264; int rr = 1 + (q >> 2); int c4 = q & 3;
               idx = rr*PROW + (c4 == 0 ? 0 : 128 + c4); }
        p[(long)idx*CSTR + ch] = 0;
    }
}

// ---- write x (fp32 NCHW) into ch12-21 (hi) / ch44-53 (lo) of buffer C.
__global__ void xfill(const float* __restrict__ x, unsigned short* __restrict__ bufC, int b0)
{
    int s = blockIdx.y, gb = b0 + s;
    int px = blockIdx.x*256 + threadIdx.x;        // 0..16383 interior
    int rr = px >> 7, cc = px & 127;
    long dst = (long)s*BUFEL + ((long)(rr+1)*PROW + cc + 1)*CSTR;
#pragma unroll
    for (int c = 0; c < 10; ++c) {
        float v = x[((long)gb*10 + c)*HW + px];
        unsigned short hb = f2bf(v);
        unsigned short lb = f2bf(v - bf2f(hb));
        bufC[dst + 12 + c] = hb;
        bufC[dst + 44 + c] = lb;
    }
}

// ---- MFMA conv3x3 (+BN bias, ReLU): 9 shifted 16x16x32 GEMMs, 3-term
// bf16 split. Wave = one o-tile of 16; A-frags (weights) for all 9 shifts
// held in regs; B-frags = contiguous 16B NHWC loads.
template<int CO>
__global__ __launch_bounds__(256, 3)
void conv_m(const unsigned short* __restrict__ actIn, unsigned short* __restrict__ actOut,
            const unsigned short* __restrict__ wbf, int slotEl,
            const float* __restrict__ bias, int bnOff, int b0)
{
    const int s = blockIdx.y, gb = b0 + s;
    const int o0 = blockIdx.z << 4;
    const int l = threadIdx.x & 63, wv = threadIdx.x >> 6;
    const int ln = l & 15, quad = l >> 4;

    const unsigned short* wbase = wbf + (long)gb*WSMP + slotEl + (o0+ln)*32 + quad*8;
    bf8 Ah[9], Al[9];
#pragma unroll
    for (int sh = 0; sh < 9; ++sh) {
        Ah[sh] = *(const bf8*)(wbase + sh*2048);
        Al[sh] = *(const bf8*)(wbase + sh*2048 + 1024);
    }
    f4v binit = *(const f4v*)(bias + bnOff + o0 + quad*4);

    const unsigned short* ibase = actIn + (long)s*BUFEL + quad*8;
    unsigned short* obb = actOut + (long)s*BUFEL;

#pragma unroll 1
    for (int i = 0; i < 4; ++i) {
        int t = blockIdx.x*16 + wv*4 + i;       // 1024 tiles: row r, 16-px col group
        int rr = t >> 3, c0 = (t & 7) << 4;
        long px = (long)(rr+1)*PROW + c0 + 1 + ln;
        const unsigned short* bp0 = ibase + px*CSTR;
        f4v acc = binit;
#pragma unroll
        for (int kr = 0; kr < 3; ++kr)
#pragma unroll
            for (int kc = 0; kc < 3; ++kc) {
                const unsigned short* bp = bp0 + ((kr-1)*PROW + (kc-1))*CSTR;
                bf8 Bh = *(const bf8*)(bp);
                bf8 Bl = *(const bf8*)(bp + 32);
                int sh = kr*3 + kc;
                acc = __builtin_amdgcn_mfma_f32_16x16x32_bf16(Ah[sh], Bh, acc, 0,0,0);
                acc = __builtin_amdgcn_mfma_f32_16x16x32_bf16(Ah[sh], Bl, acc, 0,0,0);
                acc = __builtin_amdgcn_mfma_f32_16x16x32_bf16(Al[sh], Bh, acc, 0,0,0);
            }
        int ob = o0 + quad*4;                   // 4 consecutive out channels
        if (ob < CO) {
            s4v h, lo;
#pragma unroll
            for (int j = 0; j < 4; ++j) {
                float v = fmaxf(acc[j], 0.f);   // BN bias already in acc init
                unsigned short hb = f2bf(v);
                unsigned short lb = f2bf(v - bf2f(hb));
                h[j] = (short)hb; lo[j] = (short)lb;
            }
            unsigned short* op = obb + px*CSTR + ob;
            *(s4v*)(op)      = h;
            *(s4v*)(op + 32) = lo;
        }
    }
}

// ---- final 1x1 conv -> fp32 NCHW d_out. Single shift, no bias/ReLU.
__global__ __launch_bounds__(256, 3)
void conv_f(const unsigned short* __restrict__ actIn, float* __restrict__ outF,
            const unsigned short* __restrict__ wbf, int slotEl, int b0)
{
    const int s = blockIdx.y, gb = b0 + s;
    const int l = threadIdx.x & 63, wv = threadIdx.x >> 6;
    const int ln = l & 15, quad = l >> 4;
    const unsigned short* wbase = wbf + (long)gb*WSMP + slotEl + ln*32 + quad*8;
    bf8 Ah = *(const bf8*)(wbase);
    bf8 Al = *(const bf8*)(wbase + 1024);
    const unsigned short* ibase = actIn + (long)s*BUFEL + quad*8;

#pragma unroll 1
    for (int i = 0; i < 4; ++i) {
        int t = blockIdx.x*16 + wv*4 + i;
        int rr = t >> 3, c0 = (t & 7) << 4;
        long px = (long)(rr+1)*PROW + c0 + 1 + ln;
        const unsigned short* bp = ibase + px*CSTR;
        bf8 Bh = *(const bf8*)(bp);
        bf8 Bl = *(const bf8*)(bp + 32);
        f4v acc = {0.f, 0.f, 0.f, 0.f};
        acc = __builtin_amdgcn_mfma_f32_16x16x32_bf16(Ah, Bh, acc, 0,0,0);
        acc = __builtin_amdgcn_mfma_f32_16x16x32_bf16(Ah, Bl, acc, 0,0,0);
        acc = __builtin_amdgcn_mfma_f32_16x16x32_bf16(Al, Bh, acc, 0,0,0);
        int pxu = rr*128 + c0 + ln;
#pragma unroll
        for (int j = 0; j < 4; ++j) {
            int o = quad*4 + j;
            if (o < 11)
                outF[((long)gb*11 + o)*HW + pxu] = acc[j];
        }
    }
}

extern "C" void kernel_launch(void* const* d_in, const int* in_sizes, int n_in,
                              void* d_out, int out_size, void* d_ws, size_t ws_size,
                              hipStream_t stream)
{
    const float *x = (const float*)d_in[0], *w1 = (const float*)d_in[1],
                *w2 = (const float*)d_in[2], *w3 = (const float*)d_in[3],
                *w4 = (const float*)d_in[4], *g  = (const float*)d_in[5],
                *be = (const float*)d_in[6], *mu = (const float*)d_in[7],
                *va = (const float*)d_in[8];
    if (n_in == 9) {   // identify by size signature (fallback: dict order)
        const float* big801[2] = {nullptr, nullptr}; int n801 = 0;
        const float* bn156[4]  = {nullptr, nullptr, nullptr, nullptr}; int n156 = 0;
        const float *fx = nullptr, *fw1 = nullptr, *fw4 = nullptr;
        for (int i = 0; i < 9; ++i) {
            int sz = in_sizes[i];
            if      (sz == 10485760) fx  = (const float*)d_in[i];
            else if (sz ==   235008) fw1 = (const float*)d_in[i];
            else if (sz ==   801792) { if (n801 < 2) big801[n801++] = (const float*)d_in[i]; }
            else if (sz ==    15488) fw4 = (const float*)d_in[i];
            else if (sz ==      156) { if (n156 < 4) bn156[n156++] = (const float*)d_in[i]; }
        }
        if (fx && fw1 && fw4 && n801 == 2 && n156 == 4) {
            x = fx; w1 = fw1; w2 = big801[0]; w3 = big801[1]; w4 = fw4;
            g = bn156[0]; be = bn156[1]; mu = bn156[2]; va = bn156[3];
        }
    }
    float* out = (float*)d_out;

    // ws: [bf16 weights 21.5MB][bias 1KB][bufA|bufB|bufC, chunk samples each]
    const size_t wgtB  = (size_t)NB * WSMP * 2;          // 21,495,808
    const size_t biasB = 1024;
    const size_t hdr   = (wgtB + biasB + 255) & ~(size_t)255;
    const size_t bufB1 = (size_t)BUFEL * 2;              // 2,196,480 B / sample / buffer
    unsigned short* wbf = (unsigned short*)d_ws;
    float* bias = (float*)((char*)d_ws + wgtB);
    size_t avail = ws_size > hdr ? ws_size - hdr : bufB1 * 3;
    int chunk = (int)(avail / (3 * bufB1));
    if (chunk > NB) chunk = NB;
    if (chunk < 1)  chunk = 1;
    unsigned short* bufA = (unsigned short*)((char*)d_ws + hdr);
    unsigned short* bufBp = bufA + (long)chunk * BUFEL;
    unsigned short* bufC = bufBp + (long)chunk * BUFEL;

    prep_w<<<4096, 256, 0, stream>>>(w1, w2, w3, w4, g, be, mu, va, wbf, bias);
    zbord<<<3 * chunk, 256, 0, stream>>>(bufA);          // A,B,C contiguous

    for (int b0 = 0; b0 < NB; b0 += chunk) {
        int nb = (NB - b0 < chunk) ? (NB - b0) : chunk;
        dim3 g1(64, nb, 1), g2(64, nb, 2), gx(64, nb);
        xfill<<<gx, 256, 0, stream>>>(x, bufC, b0);
        conv_m<12><<<g1,256,0,stream>>>(bufC,  bufA,  wbf,  0*2048, bias,   0, b0);
        conv_m<12><<<g1,256,0,stream>>>(bufA,  bufBp, wbf,  9*2048, bias,  12, b0);
        conv_m<12><<<g1,256,0,stream>>>(bufBp, bufC,  wbf, 18*2048, bias,  24, b0);
        conv_m<24><<<g2,256,0,stream>>>(bufC,  bufA,  wbf, 27*2048, bias,  36, b0);
        conv_m<24><<<g2,256,0,stream>>>(bufA,  bufBp, wbf, 36*2048, bias,  60, b0);
        conv_m<12><<<g1,256,0,stream>>>(bufBp, bufC,  wbf, 45*2048, bias,  84, b0);
        conv_m<24><<<g2,256,0,stream>>>(bufC,  bufA,  wbf, 54*2048, bias,  96, b0);
        conv_m<24><<<g2,256,0,stream>>>(bufA,  bufBp, wbf, 63*2048, bias, 120, b0);
        conv_m<12><<<g1,256,0,stream>>>(bufBp, bufC,  wbf, 72*2048, bias, 144, b0);
        conv_f<<<gx,256,0,stream>>>(bufC, out, wbf, 81*2048, b0);
    }
}